// Round 4
// baseline (302.661 us; speedup 1.0000x reference)
//
#include <hip/hip_runtime.h>

// Problem constants (from reference setup_inputs)
#define BB 32
#define LL 4
#define SS 512
#define DD 768
#define D4 (DD / 4)   // 192 float4 lanes per row
#define GG 24         // NUM_SEGMENTS

typedef float floatx4 __attribute__((ext_vector_type(4)));

// Workspace layout (ints): word_bounds[BB][SS+1], seg_bounds[BB][GG+1]
#define WB_STRIDE (SS + 1)
#define SB_STRIDE (GG + 1)

// ---------------------------------------------------------------------------
// Kernel 1: per batch b —
//   wb[b][v] = lower_bound(tg_row, v)  (word g owns tokens [wb[g], wb[g+1]))
//   sb[b][v] = lower_bound(sg_row, v)  (segment t owns word slots [sb[t], sb[t+1]))
//   mask[b][j] = (j >= sg[b][511]+1)   (sg sorted -> last elem is max)
// ---------------------------------------------------------------------------
__global__ __launch_bounds__(SS) void bounds_kernel(
    const int* __restrict__ tg, const int* __restrict__ sg,
    int* __restrict__ wb, int* __restrict__ sb, float* __restrict__ mask)
{
    __shared__ int ltg[SS];
    __shared__ int lsg[SS];
    const int b = blockIdx.x;
    const int t = threadIdx.x;
    ltg[t] = tg[b * SS + t];
    lsg[t] = sg[b * SS + t];
    __syncthreads();

    {
        int v = t, lo = 0, hi = SS;
        while (lo < hi) { int m = (lo + hi) >> 1; if (ltg[m] < v) lo = m + 1; else hi = m; }
        wb[b * WB_STRIDE + t] = lo;
        if (t == 0) wb[b * WB_STRIDE + SS] = SS;
    }
    if (t <= GG) {
        int v = t, lo = 0, hi = SS;
        while (lo < hi) { int m = (lo + hi) >> 1; if (lsg[m] < v) lo = m + 1; else hi = m; }
        sb[b * SB_STRIDE + t] = lo;
    }
    if (t < GG) {
        const int seg_num = lsg[SS - 1] + 1;
        mask[b * GG + t] = (t >= seg_num) ? 1.0f : 0.0f;
    }
}

// ---------------------------------------------------------------------------
// Kernel 2 (fused, deterministic): block (t, b) owns segment t = word slots
// g in [sb[t], sb[t+1])  (segments partition [0,512) since sg is sorted and
// every slot has a segment id; absent ids give empty ranges -> seg row = 0).
// For each g: word[b,g,:] = sum_{s in [wb[g],wb[g+1])} sum_l emb[b,l,s,:]
//   (nontemporal read: emb streamed exactly once across all blocks).
// seg[b,t,:] = sum of the block's word rows — plain store, NO atomics,
// no zero-init dependency, bit-deterministic.
// ---------------------------------------------------------------------------
__global__ __launch_bounds__(D4) void fused_agg_kernel(
    const floatx4* __restrict__ emb, const int* __restrict__ wb,
    const int* __restrict__ sb,
    floatx4* __restrict__ word, floatx4* __restrict__ seg)
{
    const int t = blockIdx.x;
    const int b = blockIdx.y;
    const int d = threadIdx.x;
    const int glo = sb[b * SB_STRIDE + t];
    const int ghi = sb[b * SB_STRIDE + t + 1];

    floatx4 seg_acc = (floatx4)(0.0f);
    for (int g = glo; g < ghi; ++g) {
        const int lo = wb[b * WB_STRIDE + g];
        const int hi = wb[b * WB_STRIDE + g + 1];
        floatx4 wacc = (floatx4)(0.0f);
        for (int s = lo; s < hi; ++s) {
#pragma unroll
            for (int l = 0; l < LL; ++l) {
                wacc += __builtin_nontemporal_load(
                    &emb[((size_t)((b * LL + l) * SS + s)) * D4 + d]);
            }
        }
        word[((size_t)(b * SS + g)) * D4 + d] = wacc;
        seg_acc += wacc;
    }
    seg[((size_t)(b * GG + t)) * D4 + d] = seg_acc;
}

// ---------------------------------------------------------------------------
// Kernel 3: sent[b,:] = (1/512) * sum_t seg[b,t,:]  (seg is L2-hot, 2.3 MB)
// ---------------------------------------------------------------------------
__global__ __launch_bounds__(D4) void sent_kernel(
    const floatx4* __restrict__ seg, floatx4* __restrict__ sent)
{
    const int b = blockIdx.x;
    const int d = threadIdx.x;
    floatx4 acc = (floatx4)(0.0f);
#pragma unroll
    for (int t = 0; t < GG; ++t) {
        acc += seg[((size_t)(b * GG + t)) * D4 + d];
    }
    acc *= (1.0f / (float)SS);
    sent[(size_t)b * D4 + d] = acc;
}

extern "C" void kernel_launch(void* const* d_in, const int* in_sizes, int n_in,
                              void* d_out, int out_size, void* d_ws, size_t ws_size,
                              hipStream_t stream) {
    const float* emb = (const float*)d_in[0];           // [32,4,512,768] fp32
    const int*   tg  = (const int*)d_in[1];             // [32,512]
    const int*   sg  = (const int*)d_in[2];             // [32,512]

    float* out  = (float*)d_out;
    float* word = out;                                   // [32,512,768]
    float* sent = word + (size_t)BB * SS * DD;           // [32,768]
    float* seg  = sent + (size_t)BB * DD;                // [32,24,768]
    float* mask = seg  + (size_t)BB * GG * DD;           // [32,24]

    int* wb = (int*)d_ws;                                // [32][513]
    int* sb = wb + BB * WB_STRIDE;                       // [32][25]

    bounds_kernel<<<BB, SS, 0, stream>>>(tg, sg, wb, sb, mask);
    fused_agg_kernel<<<dim3(GG, BB), D4, 0, stream>>>(
        (const floatx4*)emb, wb, sb, (floatx4*)word, (floatx4*)seg);
    sent_kernel<<<BB, D4, 0, stream>>>((const floatx4*)seg, (floatx4*)sent);
}